// Round 1
// baseline (210.733 us; speedup 1.0000x reference)
//
#include <hip/hip_runtime.h>
#include <hip/hip_bf16.h>

// Problem: B=1, S=4096, D=4096, O=4096
//   q = fake-quant(x) per row (int8 levels, scale = 127/max(|x|,1e-5))
//   out[s,o] = (sum_d qi[s,d]*W[o,d]) * rscale[s] / weight_scale + bias[o]/weight_scale
// qi in [-128,127] int, W in {-1,0,1}: bf16 MFMA with fp32 accum is EXACT here.

#define SEQ  4096
#define DIM  4096
#define OUT  4096

typedef __bf16 bf16x8 __attribute__((ext_vector_type(8)));
typedef float f32x4 __attribute__((ext_vector_type(4)));

__device__ __forceinline__ unsigned short f2bf_exact(float f) {
    // exact for values exactly representable in bf16 (small integers here)
    union { float f; unsigned u; } c; c.f = f;
    return (unsigned short)(c.u >> 16);
}

__device__ __forceinline__ void gload_lds16(const void* g, void* lds) {
    __builtin_amdgcn_global_load_lds(
        (const __attribute__((address_space(1))) void*)g,
        (__attribute__((address_space(3))) void*)lds, 16, 0, 0);
}

// ---------------- Kernel 1: per-row activation fake-quant -> bf16 qi ----------------
__global__ __launch_bounds__(256) void quant_kernel(
    const float* __restrict__ x, unsigned short* __restrict__ q,
    float* __restrict__ rscale) {
    const int row = blockIdx.x;
    const int t = threadIdx.x;
    const int lane = t & 63, wave = t >> 6;
    const float4* xr = (const float4*)(x + (size_t)row * DIM);

    float4 r[4];
    float m = 0.0f;
#pragma unroll
    for (int i = 0; i < 4; ++i) {
        r[i] = xr[t + 256 * i];
        m = fmaxf(m, fmaxf(fmaxf(fabsf(r[i].x), fabsf(r[i].y)),
                           fmaxf(fabsf(r[i].z), fabsf(r[i].w))));
    }
    // wave64 max-reduce
#pragma unroll
    for (int off = 32; off > 0; off >>= 1)
        m = fmaxf(m, __shfl_xor(m, off, 64));
    __shared__ float red[4];
    if (lane == 0) red[wave] = m;
    __syncthreads();
    const float amax = fmaxf(fmaxf(red[0], red[1]), fmaxf(red[2], red[3]));
    const float c = fmaxf(amax, 1e-5f);
    const float scale = 127.0f / c;
    if (t == 0) rscale[row] = 1.0f / scale;

    ushort4* qr = (ushort4*)(q + (size_t)row * DIM);
#pragma unroll
    for (int i = 0; i < 4; ++i) {
        float qv0 = fminf(127.0f, fmaxf(-128.0f, rintf(r[i].x * scale)));
        float qv1 = fminf(127.0f, fmaxf(-128.0f, rintf(r[i].y * scale)));
        float qv2 = fminf(127.0f, fmaxf(-128.0f, rintf(r[i].z * scale)));
        float qv3 = fminf(127.0f, fmaxf(-128.0f, rintf(r[i].w * scale)));
        ushort4 o;
        o.x = f2bf_exact(qv0); o.y = f2bf_exact(qv1);
        o.z = f2bf_exact(qv2); o.w = f2bf_exact(qv3);
        qr[t + 256 * i] = o;
    }
}

// ---------------- Kernel 2: W fp32 {-1,0,1} -> bf16 ----------------
__global__ __launch_bounds__(256) void wconv_kernel(
    const float4* __restrict__ W4, ushort4* __restrict__ Wb4, int n4) {
    int i = blockIdx.x * blockDim.x + threadIdx.x;
    const int stride = gridDim.x * blockDim.x;
    for (; i < n4; i += stride) {
        float4 w = W4[i];
        ushort4 o;
        o.x = f2bf_exact(w.x); o.y = f2bf_exact(w.y);
        o.z = f2bf_exact(w.z); o.w = f2bf_exact(w.w);
        Wb4[i] = o;
    }
}

// ---------------- Kernel 3: bf16 GEMM C = A * B^T, fused epilogue ----------------
// A = qi [S][D] bf16, B = W [O][D] bf16 (both K-major). 128x128 tile, BK=32,
// 4 waves each owning 64x64 (4x4 frags of 16x16x32 MFMA). m97 structure.
__global__ __launch_bounds__(256) void gemm_bt_kernel(
    const unsigned short* __restrict__ A, const unsigned short* __restrict__ B,
    const float* __restrict__ rscale, const float* __restrict__ bias,
    const float* __restrict__ wscale, float* __restrict__ out) {
    __shared__ __align__(16) unsigned short As[128 * 32];
    __shared__ __align__(16) unsigned short Bs[128 * 32];
    const int t = threadIdx.x;
    const int lane = t & 63;
    const int wave = t >> 6;
    const int brow = blockIdx.y, bcol = blockIdx.x;
    const int wr = wave >> 1, wc = wave & 1;
    const int K = DIM;

    // staging: thread t copies 16B chunk p at tile byte offset p*4096 + t*16
    const int ob = t * 16;
    const int srow = ob >> 6;            // row within tile (32 bf16 = 64B per row)
    const int kcol = (ob & 63) >> 1;     // bf16 col within BK
    const size_t gA0 = (size_t)(brow * 128 + srow) * K + kcol;
    const size_t gA1 = (size_t)(brow * 128 + 64 + srow) * K + kcol;
    const size_t gB0 = (size_t)(bcol * 128 + srow) * K + kcol;
    const size_t gB1 = (size_t)(bcol * 128 + 64 + srow) * K + kcol;
    unsigned short* ldsA0 = &As[t * 8];
    unsigned short* ldsA1 = &As[2048 + t * 8];
    unsigned short* ldsB0 = &Bs[t * 8];
    unsigned short* ldsB1 = &Bs[2048 + t * 8];

    f32x4 acc[4][4] = {};

    const int fr = lane & 15;
    const int kq = (lane >> 4) * 8;
    const int aoff = (wr * 64 + fr) * 32 + kq;   // + m*512
    const int boff = (wc * 64 + fr) * 32 + kq;   // + n*512

    for (int k0 = 0; k0 < K; k0 += 32) {
        gload_lds16(A + gA0 + k0, ldsA0);
        gload_lds16(A + gA1 + k0, ldsA1);
        gload_lds16(B + gB0 + k0, ldsB0);
        gload_lds16(B + gB1 + k0, ldsB1);
        __syncthreads();
        bf16x8 af[4], bfr[4];
#pragma unroll
        for (int m = 0; m < 4; ++m) af[m] = *(const bf16x8*)&As[aoff + m * 512];
#pragma unroll
        for (int n = 0; n < 4; ++n) bfr[n] = *(const bf16x8*)&Bs[boff + n * 512];
#pragma unroll
        for (int m = 0; m < 4; ++m)
#pragma unroll
            for (int n = 0; n < 4; ++n)
                acc[m][n] = __builtin_amdgcn_mfma_f32_16x16x32_bf16(
                    af[m], bfr[n], acc[m][n], 0, 0, 0);
        __syncthreads();
    }

    // epilogue: C/D layout col=lane&15, row=(lane>>4)*4+j  (guide §3, m89-verified)
    const float invws = 1.0f / wscale[0];
    const int r0 = brow * 128 + wr * 64 + ((lane >> 4) << 2);
    const int c0 = bcol * 128 + wc * 64 + fr;
    float bv[4];
#pragma unroll
    for (int n = 0; n < 4; ++n) bv[n] = bias[c0 + n * 16] * invws;
#pragma unroll
    for (int m = 0; m < 4; ++m) {
#pragma unroll
        for (int j = 0; j < 4; ++j) {
            const int r = r0 + m * 16 + j;
            const float rs = rscale[r] * invws;
            float* orow = out + (size_t)r * OUT + c0;
#pragma unroll
            for (int n = 0; n < 4; ++n)
                orow[n * 16] = acc[m][n][j] * rs + bv[n];
        }
    }
}

extern "C" void kernel_launch(void* const* d_in, const int* in_sizes, int n_in,
                              void* d_out, int out_size, void* d_ws, size_t ws_size,
                              hipStream_t stream) {
    const float* x      = (const float*)d_in[0];
    const float* W      = (const float*)d_in[1];
    const float* bias   = (const float*)d_in[2];
    const float* wscale = (const float*)d_in[3];
    float* out = (float*)d_out;

    // workspace layout
    char* ws = (char*)d_ws;
    unsigned short* q_bf = (unsigned short*)(ws);                       // 32 MB
    unsigned short* w_bf = (unsigned short*)(ws + (size_t)33554432);    // 32 MB
    float* rscale        = (float*)(ws + (size_t)67108864);             // 16 KB

    quant_kernel<<<SEQ, 256, 0, stream>>>(x, q_bf, rscale);
    wconv_kernel<<<2048, 256, 0, stream>>>((const float4*)W, (ushort4*)w_bf,
                                           (OUT * DIM) / 4);
    dim3 grid(OUT / 128, SEQ / 128);
    gemm_bt_kernel<<<grid, 256, 0, stream>>>(q_bf, w_bf, rscale, bias, wscale, out);
}

// Round 2
// 137.150 us; speedup vs baseline: 1.5365x; 1.5365x over previous
//
#include <hip/hip_runtime.h>
#include <hip/hip_bf16.h>

// B=1, S=4096, D=4096, O=4096
//   q = fake-quant(x) per row (int8 levels, scale = 127/max(|x|,1e-5))
//   out[s,o] = (sum_d qi[s,d]*W[o,d]) * rscale[s]/ws + bias[o]/ws
// qi in [-128,127], W in {-1,0,1}: bf16 MFMA with fp32 accum is EXACT.
//
// GEMM: 256x256 tile, BK=32, ring-4 LDS pipeline (depth-3 prefetch),
// counted vmcnt(8) (never 0 in main loop), 1 barrier per K-tile,
// row-pair-interleaved + XOR-swizzled LDS (conflict-free ds_read_b128),
// linear global_load_lds dest + inverse-swizzled global source (rule #21).

#define SEQ  4096
#define DIM  4096
#define OUTD 4096
#define NT   (DIM / 32)   // 128 K-tiles

typedef __bf16 bf16x8 __attribute__((ext_vector_type(8)));
typedef float f32x4 __attribute__((ext_vector_type(4)));
typedef unsigned short u16;

__device__ __forceinline__ u16 f2bf_exact(float f) {
    union { float f; unsigned u; } c; c.f = f;
    return (u16)(c.u >> 16);
}

__device__ __forceinline__ void gload16(const void* g, void* lds) {
    __builtin_amdgcn_global_load_lds(
        (const __attribute__((address_space(1))) void*)g,
        (__attribute__((address_space(3))) void*)lds, 16, 0, 0);
}

// LDS layout per slot (per matrix): 256 rows x 32 k (bf16), stored as 128
// row-pairs of 128B. Element (r, k-byte kb) at byte:
//   (r>>1)*128 + ((((r&1)<<6) | kb) ^ (((r>>1)&3)<<4))
// -> ds_read_b128 of a 16-row fragment hits 8 distinct 16B slots (2-way, free).
__device__ __forceinline__ int ldsoff_u16(int r, int kq) {
    const int rp = r >> 1;
    const int w = (((r & 1) << 6) | (kq << 4)) ^ ((rp & 3) << 4);
    return rp * 64 + (w >> 1);
}

// ---------------- Kernel 1: per-row activation fake-quant -> bf16 qi ----------------
__global__ __launch_bounds__(256) void quant_kernel(
    const float* __restrict__ x, u16* __restrict__ q, float* __restrict__ rscale) {
    const int row = blockIdx.x;
    const int t = threadIdx.x;
    const int lane = t & 63, wave = t >> 6;
    const float4* xr = (const float4*)(x + (size_t)row * DIM);

    float4 r[4];
    float m = 0.0f;
#pragma unroll
    for (int i = 0; i < 4; ++i) {
        r[i] = xr[t + 256 * i];
        m = fmaxf(m, fmaxf(fmaxf(fabsf(r[i].x), fabsf(r[i].y)),
                           fmaxf(fabsf(r[i].z), fabsf(r[i].w))));
    }
#pragma unroll
    for (int off = 32; off > 0; off >>= 1)
        m = fmaxf(m, __shfl_xor(m, off, 64));
    __shared__ float red[4];
    if (lane == 0) red[wave] = m;
    __syncthreads();
    const float amax = fmaxf(fmaxf(red[0], red[1]), fmaxf(red[2], red[3]));
    const float scale = 127.0f / fmaxf(amax, 1e-5f);
    if (t == 0) rscale[row] = 1.0f / scale;

    ushort4* qr = (ushort4*)(q + (size_t)row * DIM);
#pragma unroll
    for (int i = 0; i < 4; ++i) {
        float q0 = fminf(127.0f, fmaxf(-128.0f, rintf(r[i].x * scale)));
        float q1 = fminf(127.0f, fmaxf(-128.0f, rintf(r[i].y * scale)));
        float q2 = fminf(127.0f, fmaxf(-128.0f, rintf(r[i].z * scale)));
        float q3 = fminf(127.0f, fmaxf(-128.0f, rintf(r[i].w * scale)));
        ushort4 o;
        o.x = f2bf_exact(q0); o.y = f2bf_exact(q1);
        o.z = f2bf_exact(q2); o.w = f2bf_exact(q3);
        qr[t + 256 * i] = o;
    }
}

// ---------------- Kernel 2: W fp32 {-1,0,1} -> bf16 ----------------
__global__ __launch_bounds__(256) void wconv_kernel(
    const float4* __restrict__ W4, ushort4* __restrict__ Wb4, int n4) {
    int i = blockIdx.x * blockDim.x + threadIdx.x;
    const int stride = gridDim.x * blockDim.x;
    for (; i < n4; i += stride) {
        float4 w = W4[i];
        ushort4 o;
        o.x = f2bf_exact(w.x); o.y = f2bf_exact(w.y);
        o.z = f2bf_exact(w.z); o.w = f2bf_exact(w.w);
        Wb4[i] = o;
    }
}

// ---------------- Kernel 3: ring-4 pipelined bf16 GEMM, fused epilogue ----------------
__global__ __launch_bounds__(512, 2) void gemm_kernel(
    const u16* __restrict__ A, const u16* __restrict__ B,
    const float* __restrict__ rscale, const float* __restrict__ bias,
    const float* __restrict__ wscale, float* __restrict__ out) {
    __shared__ __align__(16) u16 As[4 * 8192];   // 4 slots x 16KB
    __shared__ __align__(16) u16 Bs[4 * 8192];
    const int tid = threadIdx.x;
    const int lane = tid & 63, wave = tid >> 6;
    const int wr = wave >> 2, wc = wave & 3;       // 2 x 4 waves
    const int fr = lane & 15, kq = lane >> 4;

    // bijective XCD swizzle (256 % 8 == 0): each XCD owns 2 contiguous brow panels
    const int bid = blockIdx.x;
    const int swz = (bid & 7) * 32 + (bid >> 3);
    const int brow = swz >> 4, bcol = swz & 15;

    // staging source geometry: LDS dest is linear (chunk c: bytes c*8192 + tid*16);
    // inverse-swizzle applied to the GLOBAL source (involution).
    const int v = (tid & 7) ^ ((tid >> 3) & 3);
    const int ke = (v & 3) * 8;                    // k-element offset (0,8,16,24)
    const int r0 = ((tid >> 3) << 1) + (v >> 2);   // chunk0 tile-row
    const u16* gA0 = A + (size_t)(brow * 256 + r0) * DIM + ke;
    const u16* gA1 = A + (size_t)(brow * 256 + 128 + r0) * DIM + ke;
    const u16* gB0 = B + (size_t)(bcol * 256 + r0) * DIM + ke;
    const u16* gB1 = B + (size_t)(bcol * 256 + 128 + r0) * DIM + ke;
    u16* lA0 = &As[tid * 8];
    u16* lA1 = &As[4096 + tid * 8];
    u16* lB0 = &Bs[tid * 8];
    u16* lB1 = &Bs[4096 + tid * 8];

#define STAGE(T, S) do { const int _k = (T) * 32;          \
        gload16(gA0 + _k, lA0 + (S) * 8192);               \
        gload16(gA1 + _k, lA1 + (S) * 8192);               \
        gload16(gB0 + _k, lB0 + (S) * 8192);               \
        gload16(gB1 + _k, lB1 + (S) * 8192); } while (0)

    int aoff[8], boff[4];
#pragma unroll
    for (int m = 0; m < 8; ++m) aoff[m] = ldsoff_u16(wr * 128 + m * 16 + fr, kq);
#pragma unroll
    for (int n = 0; n < 4; ++n) boff[n] = ldsoff_u16(wc * 64 + n * 16 + fr, kq);

    f32x4 acc[8][4] = {};

#define COMPUTE(S) do {                                                        \
        bf16x8 af[8], bfv[4];                                                  \
        _Pragma("unroll")                                                      \
        for (int n = 0; n < 4; ++n)                                            \
            bfv[n] = *(const bf16x8*)&Bs[(S) * 8192 + boff[n]];                \
        _Pragma("unroll")                                                      \
        for (int m = 0; m < 8; ++m)                                            \
            af[m] = *(const bf16x8*)&As[(S) * 8192 + aoff[m]];                 \
        _Pragma("unroll")                                                      \
        for (int m = 0; m < 8; ++m)                                            \
            _Pragma("unroll")                                                  \
            for (int n = 0; n < 4; ++n)                                        \
                acc[m][n] = __builtin_amdgcn_mfma_f32_16x16x32_bf16(           \
                    af[m], bfv[n], acc[m][n], 0, 0, 0);                        \
    } while (0)

#define VMW(N) asm volatile("s_waitcnt vmcnt(" #N ")" ::: "memory")
#define BAR()  do { asm volatile("" ::: "memory");                             \
                    __builtin_amdgcn_s_barrier();                              \
                    asm volatile("" ::: "memory"); } while (0)

    // prologue: tiles 0..2 in flight (12 loads/wave)
    STAGE(0, 0); STAGE(1, 1); STAGE(2, 2);

    // main loop: tiles 0..123; stage runs 3 tiles ahead into the slot that was
    // fully consumed last iteration; vmcnt(8) = 2 tiles may stay in flight.
    for (int tb = 0; tb < 31; ++tb) {
        const int t = tb * 4;
        VMW(8); BAR(); STAGE(t + 3, 3); COMPUTE(0);
        VMW(8); BAR(); STAGE(t + 4, 0); COMPUTE(1);
        VMW(8); BAR(); STAGE(t + 5, 1); COMPUTE(2);
        VMW(8); BAR(); STAGE(t + 6, 2); COMPUTE(3);
    }
    // tail: tiles 124..127
    VMW(8); BAR(); STAGE(127, 3); COMPUTE(0);
    VMW(8); BAR(); COMPUTE(1);
    VMW(4); BAR(); COMPUTE(2);
    VMW(0); BAR(); COMPUTE(3);

    // epilogue: C/D layout col=lane&15, row=(lane>>4)*4+j (round-0-verified)
    const float invws = 1.0f / wscale[0];
    const int rr0 = brow * 256 + wr * 128 + (kq << 2);
    const int c0 = bcol * 256 + wc * 64 + fr;
    float bv[4];
#pragma unroll
    for (int n = 0; n < 4; ++n) bv[n] = bias[c0 + n * 16] * invws;
#pragma unroll
    for (int m = 0; m < 8; ++m) {
#pragma unroll
        for (int j = 0; j < 4; ++j) {
            const int r = rr0 + m * 16 + j;
            const float rs = rscale[r] * invws;
            float* orow = out + (size_t)r * OUTD + c0;
#pragma unroll
            for (int n = 0; n < 4; ++n)
                orow[n * 16] = acc[m][n][j] * rs + bv[n];
        }
    }
#undef STAGE
#undef COMPUTE
#undef VMW
#undef BAR
}

extern "C" void kernel_launch(void* const* d_in, const int* in_sizes, int n_in,
                              void* d_out, int out_size, void* d_ws, size_t ws_size,
                              hipStream_t stream) {
    const float* x      = (const float*)d_in[0];
    const float* W      = (const float*)d_in[1];
    const float* bias   = (const float*)d_in[2];
    const float* wscale = (const float*)d_in[3];
    float* out = (float*)d_out;

    char* ws = (char*)d_ws;
    u16* q_bf = (u16*)(ws);                            // 32 MB
    u16* w_bf = (u16*)(ws + (size_t)33554432);         // 32 MB
    float* rscale = (float*)(ws + (size_t)67108864);   // 16 KB

    quant_kernel<<<SEQ, 256, 0, stream>>>(x, q_bf, rscale);
    wconv_kernel<<<2048, 256, 0, stream>>>((const float4*)W, (ushort4*)w_bf,
                                           (OUTD * DIM) / 4);
    gemm_kernel<<<256, 512, 0, stream>>>(q_bf, w_bf, rscale, bias, wscale, out);
}

// Round 3
// 92.876 us; speedup vs baseline: 2.2690x; 1.4767x over previous
//
#include <hip/hip_runtime.h>
#include <hip/hip_bf16.h>

// B=1, S=4096, D=4096, O=4096
//   q = fake-quant(x) per row (int8 levels, scale = 127/max(|x|,1e-5))
//   out[s,o] = (sum_d qi[s,d]*W[o,d]) * rscale[s]/ws + bias[o]/ws
// qi in [-128,127], W in {-1,0,1}: i8 MFMA with i32 accum is EXACT (|sum|<2^19).
//
// GEMM: 256x256 tile, BK=64 (i8 row = 64B, byte-identical geometry to R2's
// BK=32 bf16 -> same verified conflict-free LDS swizzle + source mapping),
// ring-4 LDS pipeline, counted vmcnt(8), 1 barrier per K-tile,
// mfma_i32_16x16x64_i8 at ~2x bf16 rate.

#define SEQ  4096
#define DIM  4096
#define OUTD 4096

typedef int i32x4 __attribute__((ext_vector_type(4)));
typedef unsigned char u8;

__device__ __forceinline__ void gload16(const void* g, void* lds) {
    __builtin_amdgcn_global_load_lds(
        (const __attribute__((address_space(1))) void*)g,
        (__attribute__((address_space(3))) void*)lds, 16, 0, 0);
}

// LDS layout per slot (per matrix): 256 rows x 64B (i8), stored as 128
// row-pairs of 128B. Element (r, 16B-quarter kq) at byte:
//   (r>>1)*128 + ((((r&1)<<6) | (kq<<4)) ^ (((r>>1)&3)<<4))
// Within every consecutive 8-lane phase of a ds_read_b128, the 8 16B-slots
// are distinct -> conflict-free (verified R2: SQ_LDS_BANK_CONFLICT == 0).
__device__ __forceinline__ int ldsoff(int r, int kq) {
    const int rp = r >> 1;
    const int w = (((r & 1) << 6) | (kq << 4)) ^ ((rp & 3) << 4);
    return rp * 128 + w;
}

// ---------------- Kernel 1: per-row activation fake-quant -> i8 qi ----------------
__global__ __launch_bounds__(256) void quant_kernel(
    const float* __restrict__ x, char* __restrict__ q, float* __restrict__ rscale) {
    const int row = blockIdx.x;
    const int t = threadIdx.x;
    const int lane = t & 63, wave = t >> 6;
    const float4* xr = (const float4*)(x + (size_t)row * DIM);

    float4 r[4];
    float m = 0.0f;
#pragma unroll
    for (int i = 0; i < 4; ++i) {
        r[i] = xr[t + 256 * i];
        m = fmaxf(m, fmaxf(fmaxf(fabsf(r[i].x), fabsf(r[i].y)),
                           fmaxf(fabsf(r[i].z), fabsf(r[i].w))));
    }
#pragma unroll
    for (int off = 32; off > 0; off >>= 1)
        m = fmaxf(m, __shfl_xor(m, off, 64));
    __shared__ float red[4];
    if (lane == 0) red[wave] = m;
    __syncthreads();
    const float amax = fmaxf(fmaxf(red[0], red[1]), fmaxf(red[2], red[3]));
    const float scale = 127.0f / fmaxf(amax, 1e-5f);
    if (t == 0) rscale[row] = 1.0f / scale;

    char4* qr = (char4*)(q + (size_t)row * DIM);
#pragma unroll
    for (int i = 0; i < 4; ++i) {
        float q0 = fminf(127.0f, fmaxf(-128.0f, rintf(r[i].x * scale)));
        float q1 = fminf(127.0f, fmaxf(-128.0f, rintf(r[i].y * scale)));
        float q2 = fminf(127.0f, fmaxf(-128.0f, rintf(r[i].z * scale)));
        float q3 = fminf(127.0f, fmaxf(-128.0f, rintf(r[i].w * scale)));
        char4 o;
        o.x = (signed char)q0; o.y = (signed char)q1;
        o.z = (signed char)q2; o.w = (signed char)q3;
        qr[t + 256 * i] = o;
    }
}

// ---------------- Kernel 2: W fp32 {-1,0,1} -> i8 ----------------
__global__ __launch_bounds__(256) void wconv_kernel(
    const float4* __restrict__ W4, char4* __restrict__ Wb4, int n4) {
    int i = blockIdx.x * blockDim.x + threadIdx.x;
    const int stride = gridDim.x * blockDim.x;
    for (; i < n4; i += stride) {
        float4 w = W4[i];
        char4 o;
        o.x = (signed char)w.x; o.y = (signed char)w.y;
        o.z = (signed char)w.z; o.w = (signed char)w.w;
        Wb4[i] = o;
    }
}

// ---------------- Kernel 3: ring-4 pipelined i8 GEMM, fused epilogue ----------------
__global__ __launch_bounds__(512, 2) void gemm_kernel(
    const u8* __restrict__ A, const u8* __restrict__ B,
    const float* __restrict__ rscale, const float* __restrict__ bias,
    const float* __restrict__ wscale, float* __restrict__ out) {
    __shared__ __align__(16) u8 As[4 * 16384];   // 4 slots x 16KB
    __shared__ __align__(16) u8 Bs[4 * 16384];
    const int tid = threadIdx.x;
    const int lane = tid & 63, wave = tid >> 6;
    const int wr = wave >> 2, wc = wave & 3;       // 2 x 4 waves
    const int fr = lane & 15, kq = lane >> 4;

    // bijective XCD swizzle (256 % 8 == 0)
    const int bid = blockIdx.x;
    const int swz = (bid & 7) * 32 + (bid >> 3);
    const int brow = swz >> 4, bcol = swz & 15;

    // staging: LDS dest linear (thread t -> bytes t*16 of each 8KB chunk);
    // inverse swizzle applied to the GLOBAL source (involution).
    const int v = (tid & 7) ^ ((tid >> 3) & 3);
    const int kb = (v & 3) * 16;                   // byte offset within 64B row
    const int r0 = ((tid >> 3) << 1) + (v >> 2);   // chunk0 tile-row
    const u8* gA0 = A + (size_t)(brow * 256 + r0) * DIM + kb;
    const u8* gA1 = A + (size_t)(brow * 256 + 128 + r0) * DIM + kb;
    const u8* gB0 = B + (size_t)(bcol * 256 + r0) * DIM + kb;
    const u8* gB1 = B + (size_t)(bcol * 256 + 128 + r0) * DIM + kb;
    u8* lA0 = &As[tid * 16];
    u8* lA1 = &As[8192 + tid * 16];
    u8* lB0 = &Bs[tid * 16];
    u8* lB1 = &Bs[8192 + tid * 16];

#define STAGE(T, S) do { const int _k = (T) * 64;          \
        gload16(gA0 + _k, lA0 + (S) * 16384);              \
        gload16(gA1 + _k, lA1 + (S) * 16384);              \
        gload16(gB0 + _k, lB0 + (S) * 16384);              \
        gload16(gB1 + _k, lB1 + (S) * 16384); } while (0)

    int aoff[8], boff[4];
#pragma unroll
    for (int m = 0; m < 8; ++m) aoff[m] = ldsoff(wr * 128 + m * 16 + fr, kq);
#pragma unroll
    for (int n = 0; n < 4; ++n) boff[n] = ldsoff(wc * 64 + n * 16 + fr, kq);

    i32x4 acc[8][4] = {};

#define COMPUTE(S) do {                                                        \
        i32x4 af[8], bfv[4];                                                   \
        _Pragma("unroll")                                                      \
        for (int n = 0; n < 4; ++n)                                            \
            bfv[n] = *(const i32x4*)&Bs[(S) * 16384 + boff[n]];                \
        _Pragma("unroll")                                                      \
        for (int m = 0; m < 8; ++m)                                            \
            af[m] = *(const i32x4*)&As[(S) * 16384 + aoff[m]];                 \
        _Pragma("unroll")                                                      \
        for (int m = 0; m < 8; ++m)                                            \
            _Pragma("unroll")                                                  \
            for (int n = 0; n < 4; ++n)                                        \
                acc[m][n] = __builtin_amdgcn_mfma_i32_16x16x64_i8(             \
                    af[m], bfv[n], acc[m][n], 0, 0, 0);                        \
    } while (0)

#define VMW(N) asm volatile("s_waitcnt vmcnt(" #N ")" ::: "memory")
#define BAR()  do { asm volatile("" ::: "memory");                             \
                    __builtin_amdgcn_s_barrier();                              \
                    asm volatile("" ::: "memory"); } while (0)

    // 64 K-tiles of BK=64. Prologue: tiles 0..2 in flight.
    STAGE(0, 0); STAGE(1, 1); STAGE(2, 2);

    for (int tb = 0; tb < 15; ++tb) {
        const int t = tb * 4;
        VMW(8); BAR(); STAGE(t + 3, 3); COMPUTE(0);
        VMW(8); BAR(); STAGE(t + 4, 0); COMPUTE(1);
        VMW(8); BAR(); STAGE(t + 5, 1); COMPUTE(2);
        VMW(8); BAR(); STAGE(t + 6, 2); COMPUTE(3);
    }
    // tail: tiles 60..63
    VMW(8); BAR(); STAGE(63, 3); COMPUTE(0);
    VMW(8); BAR(); COMPUTE(1);
    VMW(4); BAR(); COMPUTE(2);
    VMW(0); BAR(); COMPUTE(3);

    // epilogue: C/D layout col=lane&15, row=(lane>>4)*4+j (dtype-independent)
    const float invws = 1.0f / wscale[0];
    const int rr0 = brow * 256 + wr * 128 + (kq << 2);
    const int c0 = bcol * 256 + wc * 64 + fr;
    float bv[4];
#pragma unroll
    for (int n = 0; n < 4; ++n) bv[n] = bias[c0 + n * 16] * invws;
#pragma unroll
    for (int m = 0; m < 8; ++m) {
#pragma unroll
        for (int j = 0; j < 4; ++j) {
            const int r = rr0 + m * 16 + j;
            const float rs = rscale[r] * invws;
            float* orow = out + (size_t)r * OUTD + c0;
#pragma unroll
            for (int n = 0; n < 4; ++n)
                orow[n * 16] = (float)acc[m][n][j] * rs + bv[n];
        }
    }
#undef STAGE
#undef COMPUTE
#undef VMW
#undef BAR
}

extern "C" void kernel_launch(void* const* d_in, const int* in_sizes, int n_in,
                              void* d_out, int out_size, void* d_ws, size_t ws_size,
                              hipStream_t stream) {
    const float* x      = (const float*)d_in[0];
    const float* W      = (const float*)d_in[1];
    const float* bias   = (const float*)d_in[2];
    const float* wscale = (const float*)d_in[3];
    float* out = (float*)d_out;

    char* ws = (char*)d_ws;
    char* q_i8 = ws;                                   // 16 MB
    char* w_i8 = ws + (size_t)16777216;                // 16 MB
    float* rscale = (float*)(ws + (size_t)33554432);   // 16 KB

    quant_kernel<<<SEQ, 256, 0, stream>>>(x, q_i8, rscale);
    wconv_kernel<<<4096, 256, 0, stream>>>((const float4*)W, (char4*)w_i8,
                                           (OUTD * DIM) / 4);
    gemm_kernel<<<256, 512, 0, stream>>>((const u8*)q_i8, (const u8*)w_i8,
                                         rscale, bias, wscale, out);
}